// Round 6
// baseline (200.355 us; speedup 1.0000x reference)
//
#include <hip/hip_runtime.h>

// BagOfWords: input [1024, 512] int32 tokens in [0, 50257).
// Output [1024, 50256] float32: per-row histogram, vocab bin 0 dropped.
//
// R9: wide-chunk mask-gated streaming (CHUNK 4096 -> 8192).
//
// Model fitted across R0-R5 (all rounds consistent): dur = 123 us poison
// fill + per-dispatch fixed cost X (~20 us: launch + end-of-dispatch store
// drain) + kernel work. Fused kernel K ~= 52 us of which ~31 us is the
// mandatory 205.8 MB store stream at the ~6.7 TB/s issue ceiling. Three
// different store-phase structures (R0 readback / R2 persistent / R5
// mask-gated) all measured identical -> store-data path is NOT the
// bottleneck; the residual ~20 us is block-lifecycle overhead (13312
// blocks x {cold token-load wait ~600 cyc, 20 KB LDS zero, 3 barriers,
// mask phase}). The rocclr fill hits 6.7 TB/s at 10% occupancy -> BW needs
// long per-thread store runs, not waves.
//
// This round: halve lifecycles -> CHUNK=8192 (32 KB hist + 8 KB mask =
// 40 KB LDS, 4 blocks/CU, 16 waves/CU). 7 blocks/row (6 full + 1104 tail),
// 7168 blocks total; 8 float4 stores/thread. Store phase = pure zero-burst
// (mask==0 groups, zero-constant data, back-to-back) then rare sparse pass
// (mask!=0 groups, ds_read_b128 + cvt); the two passes write DISJOINT
// addresses -> no ordering hazard, no vmcnt drain anywhere.
// Plain stores, NOT nontemporal (R4: nt bypasses MALL absorption, +10 us).

#define BATCH 1024
#define SEQ 512
#define VOCAB 50257
#define OUT_COLS (VOCAB - 1)   // 50256
#define CHUNK 8192
#define NGROUP (CHUNK / 4)     // 2048 mask groups of 4 bins
#define NBLK_PER_ROW 7         // 6*8192 = 49152 + 1104-col tail
#define BLOCK 256

// LDS-only barrier: waits ds ops (lgkmcnt) but does NOT drain global stores
// (__syncthreads would emit s_waitcnt vmcnt(0) and stall the store pipe).
#define LDS_BAR()                                              \
    do {                                                       \
        asm volatile("s_waitcnt lgkmcnt(0)" ::: "memory");     \
        __builtin_amdgcn_s_barrier();                          \
        asm volatile("" ::: "memory");                         \
    } while (0)

__global__ __launch_bounds__(BLOCK) void bow_widechunk_kernel(
    const int* __restrict__ tokens, float* __restrict__ out) {
    __shared__ unsigned int hist[CHUNK];   // 32 KB
    __shared__ unsigned int mask[NGROUP];  // 8 KB

    const int t  = threadIdx.x;
    const int c0 = blockIdx.x * CHUNK;
    const int b  = blockIdx.y;

    // Issue the token load first; its wait lands after LDS zeroing + barrier.
    const int2 tk = ((const int2*)(tokens + (size_t)b * SEQ))[t];

    // Zero hist (8x uint4/thread) and mask (2x uint4/thread).
    const uint4 z4 = make_uint4(0u, 0u, 0u, 0u);
    #pragma unroll
    for (int k = 0; k < 8; ++k)
        *(uint4*)&hist[t * 4 + k * (BLOCK * 4)] = z4;
    #pragma unroll
    for (int k = 0; k < 2; ++k)
        *(uint4*)&mask[t * 4 + k * (BLOCK * 4)] = z4;

    LDS_BAR();

    // Histogram + mark occupied 4-bin groups. tok==0 dropped via unsigned
    // underflow (tok-1-c0 wraps huge). Mask write races are benign (all 1u).
    unsigned int r;
    r = (unsigned int)(tk.x - 1 - c0);
    if (r < CHUNK) { atomicAdd(&hist[r], 1u); mask[r >> 2] = 1u; }
    r = (unsigned int)(tk.y - 1 - c0);
    if (r < CHUNK) { atomicAdd(&hist[r], 1u); mask[r >> 2] = 1u; }

    LDS_BAR();

    float* orow = out + (size_t)b * OUT_COLS + c0;
    const int ncols = (c0 + CHUNK <= OUT_COLS) ? CHUNK : (OUT_COLS - c0);

    // Batch all 8 mask words (2 uint4 reads, ONE lgkm wait).
    unsigned int m[8];
    #pragma unroll
    for (int k = 0; k < 2; ++k) {
        const uint4 mw = *(const uint4*)&mask[t * 4 + k * (BLOCK * 4)];
        m[k * 4 + 0] = mw.x; m[k * 4 + 1] = mw.y;
        m[k * 4 + 2] = mw.z; m[k * 4 + 3] = mw.w;
    }
    // NOTE: group index for m[k*4+j] is (t*4 + k*1024 + j)?? -- NO. Keep the
    // simple per-word mapping below instead (scalar reads, still batched).

    // Re-read masks with the store-phase mapping: group g = t + k*BLOCK.
    #pragma unroll
    for (int k = 0; k < 8; ++k)
        m[k] = mask[t + k * BLOCK];

    // Pass 1: pure zero-burst (no LDS dependency, back-to-back stores).
    const float4 zf = make_float4(0.f, 0.f, 0.f, 0.f);
    #pragma unroll
    for (int k = 0; k < 8; ++k) {
        const int base = t * 4 + k * (BLOCK * 4);  // = 4 * group
        if (base < ncols && m[k] == 0u)
            *(float4*)(orow + base) = zf;
    }

    // Pass 2: rare sparse groups (~80/block): LDS read + cvt + store.
    // Disjoint addresses from pass 1 (m[k]!=0 vs ==0).
    #pragma unroll
    for (int k = 0; k < 8; ++k) {
        const int base = t * 4 + k * (BLOCK * 4);
        if (base < ncols && m[k] != 0u) {
            const uint4 h = *(const uint4*)&hist[base];
            *(float4*)(orow + base) = make_float4(
                (float)h.x, (float)h.y, (float)h.z, (float)h.w);
        }
    }
}

extern "C" void kernel_launch(void* const* d_in, const int* in_sizes, int n_in,
                              void* d_out, int out_size, void* d_ws, size_t ws_size,
                              hipStream_t stream) {
    const int* tokens = (const int*)d_in[0];
    float* out = (float*)d_out;

    bow_widechunk_kernel<<<dim3(NBLK_PER_ROW, BATCH), dim3(BLOCK), 0, stream>>>(
        tokens, out);
}